// Round 3
// baseline (782.411 us; speedup 1.0000x reference)
//
#include <hip/hip_runtime.h>

// ---------- common ----------
typedef unsigned short u16;
typedef unsigned int   u32;
typedef __attribute__((ext_vector_type(4))) float f32x4;
typedef __attribute__((ext_vector_type(8))) short bf16x8;

#define MFMA_B16(a,b,c) __builtin_amdgcn_mfma_f32_16x16x32_bf16((a),(b),(c),0,0,0)

__device__ __forceinline__ u16 f2bf(float f){
  u32 u = __builtin_bit_cast(u32, f);
  u32 r = (u + 0x7FFFu + ((u >> 16) & 1u)) >> 16;   // round-to-nearest-even
  return (u16)r;
}
__device__ __forceinline__ float bf2f(u16 h){
  u32 u = ((u32)h) << 16;
  return __builtin_bit_cast(float, u);
}
// async global->LDS, 16B per lane; LDS dest is wave-uniform base (+lane*16 implicit)
__device__ __forceinline__ void gload16(const void* g, void* l){
  __builtin_amdgcn_global_load_lds((const __attribute__((address_space(1))) void*)g,
                                   (__attribute__((address_space(3))) void*)l, 16, 0, 0);
}

// ---------- packing kernels ----------
// x (N,E) f32 -> xh, xl bf16 planes
__global__ __launch_bounds__(256) void pack_x2(const float* __restrict__ x,
                                               u16* __restrict__ xh, u16* __restrict__ xl){
  const int i = blockIdx.x*256 + threadIdx.x;
  const float v = x[i];
  const u16 hi = f2bf(v);
  xh[i] = hi;
  xl[i] = f2bf(v - bf2f(hi));
}

// W_Q/K/V (H,E,D) f32 -> BT planes [6144][2048] (row j = t*2048+h*128+d, col k=e), hi & lo
__global__ __launch_bounds__(256) void pack_qkv2(const float* __restrict__ WQ, const float* __restrict__ WK,
                                                 const float* __restrict__ WV,
                                                 u16* __restrict__ outh, u16* __restrict__ outl){
  __shared__ float t32[32][33];
  const int tid = threadIdx.x;
  const int tx = tid & 31, ty = tid >> 5;
  const int et = blockIdx.x >> 2, dt = blockIdx.x & 3;   // e-tile (64), d-tile (4)
  const int hh = blockIdx.y, tt = blockIdx.z;
  const float* W = (tt == 0 ? WQ : (tt == 1 ? WK : WV)) + (size_t)hh*2048*128;
  #pragma unroll
  for (int i = 0; i < 4; i++)
    t32[ty + i*8][tx] = W[(size_t)(et*32 + ty + i*8)*128 + dt*32 + tx];
  __syncthreads();
  const int j0 = tt*2048 + hh*128 + dt*32;
  #pragma unroll
  for (int i = 0; i < 4; i++){
    const float v = t32[tx][ty + i*8];
    const u16 hi = f2bf(v);
    const u16 lo = f2bf(v - bf2f(hi));
    const size_t idx = (size_t)(j0 + ty + i*8)*2048 + (et*32 + tx);
    outh[idx] = hi; outl[idx] = lo;
  }
}

// in (R,C) f32 -> outh/outl (C,R) bf16 hi/lo planes (transpose + split)
__global__ __launch_bounds__(256) void tpack2(const float* __restrict__ in,
                                              u16* __restrict__ outh, u16* __restrict__ outl,
                                              int R, int C){
  __shared__ float t32[32][33];
  const int tid = threadIdx.x;
  const int tx = tid & 31, ty = tid >> 5;
  const int c0 = blockIdx.x*32, r0 = blockIdx.y*32;
  #pragma unroll
  for (int i = 0; i < 4; i++)
    t32[ty + i*8][tx] = in[(size_t)(r0 + ty + i*8)*C + c0 + tx];
  __syncthreads();
  #pragma unroll
  for (int i = 0; i < 4; i++){
    const float v = t32[tx][ty + i*8];
    const u16 hi = f2bf(v);
    const u16 lo = f2bf(v - bf2f(hi));
    const size_t idx = (size_t)(c0 + ty + i*8)*R + r0 + tx;
    outh[idx] = hi; outl[idx] = lo;
  }
}

// ---------- GEMM: C(M,N) = A(M,K)*BT(N,K)^T with hi/lo plane phases ----------
// NS=1: Ah*Bh. NS=2: Ah*Bh + Ah*Bl. NS=3: Ah*Bh + Ah*Bl + Al*Bh.
// EPI 0: QKV split-write   1: f32 + res    2: bias+relu -> bf16    3: bias + res -> f32
template<int NS, int EPI>
__global__ __launch_bounds__(256) void gemm_bt(
    const u16* __restrict__ Ah, const u16* __restrict__ Al,
    const u16* __restrict__ Bh, const u16* __restrict__ Bl,
    float* __restrict__ outf, u16* __restrict__ outb,
    const float* __restrict__ bias, const float* __restrict__ res,
    u16* __restrict__ qh, u16* __restrict__ ql,
    u16* __restrict__ kh, u16* __restrict__ kl,
    u16* __restrict__ vTh,
    int M, int N, int K)
{
  __shared__ u16 As[128*64];
  __shared__ u16 Bs[128*64];
  const int tid = threadIdx.x;
  const int lane = tid & 63;
  const int w = tid >> 6;
  const int l15 = lane & 15, lh = lane >> 4;
  const int nbx = N >> 7;
  // XCD-bijective swizzle (grid always divisible by 8 here)
  const int bsw = ((int)blockIdx.x & 7)*((int)gridDim.x >> 3) + ((int)blockIdx.x >> 3);
  const int bx = bsw % nbx, by = bsw / nbx;
  const int m0 = by << 7, n0 = bx << 7;
  const int wm = (w >> 1) << 6, wn = (w & 1) << 6;

  f32x4 acc[4][4] = {};

  const int KV = NS * K;
  for (int k0v = 0; k0v < KV; k0v += 64){
    const u16* Ap; const u16* Bp; int kk;
    if (NS == 1){ Ap = Ah; Bp = Bh; kk = k0v; }
    else if (NS == 2){
      if (k0v < K){ Ap = Ah; Bp = Bh; kk = k0v; }
      else        { Ap = Ah; Bp = Bl; kk = k0v - K; }
    } else {
      if (k0v < K)        { Ap = Ah; Bp = Bh; kk = k0v; }
      else if (k0v < 2*K) { Ap = Ah; Bp = Bl; kk = k0v - K; }
      else                { Ap = Al; Bp = Bh; kk = k0v - 2*K; }
    }
    __syncthreads();
    #pragma unroll
    for (int q = 0; q < 4; q++){          // A tile 128 rows x 64 cols, chunk-swizzled source
      int s = q*256 + tid;
      int row = s >> 3, c = (s & 7) ^ (row & 7);
      gload16(Ap + (size_t)(m0+row)*K + kk + c*8, As + (q*256 + (tid & 192))*8);
    }
    #pragma unroll
    for (int q = 0; q < 4; q++){          // B tile 128 rows x 64 cols
      int s = q*256 + tid;
      int row = s >> 3, c = (s & 7) ^ (row & 7);
      gload16(Bp + (size_t)(n0+row)*K + kk + c*8, Bs + (q*256 + (tid & 192))*8);
    }
    asm volatile("s_waitcnt vmcnt(0)" ::: "memory");
    __syncthreads();
    #pragma unroll
    for (int kt = 0; kt < 2; kt++){
      bf16x8 af[4], bfr[4];
      #pragma unroll
      for (int m = 0; m < 4; m++){
        int row = wm + m*16 + l15;
        int c = (kt*4 + lh) ^ (row & 7);
        af[m] = *(const bf16x8*)(As + row*64 + c*8);
      }
      #pragma unroll
      for (int n = 0; n < 4; n++){
        int row = wn + n*16 + l15;
        int c = (kt*4 + lh) ^ (row & 7);
        bfr[n] = *(const bf16x8*)(Bs + row*64 + c*8);
      }
      #pragma unroll
      for (int m = 0; m < 4; m++)
        #pragma unroll
        for (int n = 0; n < 4; n++)
          acc[m][n] = MFMA_B16(af[m], bfr[n], acc[m][n]);
    }
  }

  // epilogue: C/D layout col=lane&15, row=(lane>>4)*4+r
  #pragma unroll
  for (int m = 0; m < 4; m++){
    #pragma unroll
    for (int n = 0; n < 4; n++){
      const int rbase = m0 + wm + m*16 + lh*4;
      const int col = n0 + wn + n*16 + l15;
      if (EPI == 0){
        const int plane = col >> 11;      // 0=Q 1=K 2=V
        const int cj = col & 2047;
        if (plane == 2){
          ushort4 h4 = make_ushort4(f2bf(acc[m][n][0]), f2bf(acc[m][n][1]),
                                    f2bf(acc[m][n][2]), f2bf(acc[m][n][3]));
          *(ushort4*)(vTh + (size_t)cj*2048 + rbase) = h4;   // V transposed [hd][n]
        } else {
          u16* hp = (plane == 0) ? qh : kh;
          u16* lp = (plane == 0) ? ql : kl;
          #pragma unroll
          for (int r = 0; r < 4; r++){
            float v = acc[m][n][r];
            u16 hi = f2bf(v);
            u16 lo = f2bf(v - bf2f(hi));
            hp[(size_t)(rbase+r)*2048 + cj] = hi;
            lp[(size_t)(rbase+r)*2048 + cj] = lo;
          }
        }
      } else if (EPI == 1){
        #pragma unroll
        for (int r = 0; r < 4; r++){
          size_t idx = (size_t)(rbase+r)*N + col;
          outf[idx] = acc[m][n][r] + res[idx];
        }
      } else if (EPI == 2){
        const float b = bias[col];
        #pragma unroll
        for (int r = 0; r < 4; r++){
          float v = acc[m][n][r] + b;
          outb[(size_t)(rbase+r)*N + col] = f2bf(v > 0.f ? v : 0.f);
        }
      } else {
        const float b = bias[col];
        #pragma unroll
        for (int r = 0; r < 4; r++){
          size_t idx = (size_t)(rbase+r)*N + col;
          outf[idx] = acc[m][n][r] + b + res[idx];
        }
      }
    }
  }
}

// ---------- flash attention (causal), 4 waves x 16 q-rows, KV tile 64 ----------
// Q,K hi/lo (3-term QK^T); V, P single bf16 (1-term PV); out single plane
__global__ __launch_bounds__(256) void attn_k(
    const u16* __restrict__ qh, const u16* __restrict__ ql,
    const u16* __restrict__ kh, const u16* __restrict__ kl,
    const u16* __restrict__ vT, u16* __restrict__ atth)
{
  __shared__ u16 Khs[64*128];
  __shared__ u16 Kls[64*128];
  __shared__ u16 Vhs[128*64];
  __shared__ u16 Phs[4*16*64];

  const int tid = threadIdx.x;
  const int lane = tid & 63;
  const int w = tid >> 6;
  const int l15 = lane & 15, lh = lane >> 4;
  const int h = blockIdx.y;
  const int qb = blockIdx.x;
  const int qbase = qb << 6;
  const float scale = 0.088388347648318447f;  // 1/sqrt(128)

  bf16x8 qfh[4], qfl[4];
  {
    const int qrow = qbase + w*16 + l15;
    const u16* ph = qh + (size_t)qrow*2048 + h*128 + lh*8;
    const u16* pl = ql + (size_t)qrow*2048 + h*128 + lh*8;
    #pragma unroll
    for (int kt = 0; kt < 4; kt++){
      qfh[kt] = *(const bf16x8*)(ph + kt*32);
      qfl[kt] = *(const bf16x8*)(pl + kt*32);
    }
  }

  f32x4 acco[8] = {};
  float mrun[4] = {-1e30f,-1e30f,-1e30f,-1e30f};
  float lrun[4] = {0.f,0.f,0.f,0.f};
  const int qrow0 = qbase + w*16 + lh*4;
  u16* pwh = Phs + w*1024;

  const int nkv = qb + 1;
  for (int kvt = 0; kvt < nkv; kvt++){
    const int kv0 = kvt << 6;
    __syncthreads();
    // K tiles are [64 rows][128 cols] = 16 chunks/row: row = s>>4, chunk = s&15
    #pragma unroll
    for (int q = 0; q < 4; q++){
      int s = q*256 + tid;
      int row = s >> 4, c = (s & 15) ^ (row & 7);
      gload16(kh + (size_t)(kv0+row)*2048 + h*128 + c*8, Khs + (q*256 + (tid & 192))*8);
    }
    #pragma unroll
    for (int q = 0; q < 4; q++){
      int s = q*256 + tid;
      int row = s >> 4, c = (s & 15) ^ (row & 7);
      gload16(kl + (size_t)(kv0+row)*2048 + h*128 + c*8, Kls + (q*256 + (tid & 192))*8);
    }
    // V tile is [128 rows][64 cols] = 8 chunks/row: row = s>>3, chunk = s&7
    #pragma unroll
    for (int q = 0; q < 4; q++){
      int s = q*256 + tid;
      int d = s >> 3, c = (s & 7) ^ (d & 7);
      gload16(vT + (size_t)(h*128+d)*2048 + kv0 + c*8, Vhs + (q*256 + (tid & 192))*8);
    }
    asm volatile("s_waitcnt vmcnt(0)" ::: "memory");
    __syncthreads();

    // S = Q K^T (split-2: hi*hi + hi*lo + lo*hi)
    f32x4 sac[4] = {};
    #pragma unroll
    for (int n = 0; n < 4; n++){
      const int kvr = n*16 + l15;
      const u16* kb  = Khs + kvr*128;
      const u16* klb = Kls + kvr*128;
      const int sw = kvr & 7;
      #pragma unroll
      for (int kt = 0; kt < 4; kt++){
        const int c = (kt*4 + lh) ^ sw;
        bf16x8 bh = *(const bf16x8*)(kb + c*8);
        bf16x8 bl = *(const bf16x8*)(klb + c*8);
        sac[n] = MFMA_B16(qfh[kt], bh, sac[n]);
        sac[n] = MFMA_B16(qfh[kt], bl, sac[n]);
        sac[n] = MFMA_B16(qfl[kt], bh, sac[n]);
      }
    }

    // online softmax (fp32)
    float p[4][4];
    float tm[4] = {-1e30f,-1e30f,-1e30f,-1e30f};
    #pragma unroll
    for (int n = 0; n < 4; n++){
      const int kvg = kv0 + n*16 + l15;
      #pragma unroll
      for (int r = 0; r < 4; r++){
        float s = sac[n][r] * scale;
        if (kvg > qrow0 + r) s = -1e30f;   // causal mask
        p[n][r] = s;
        tm[r] = fmaxf(tm[r], s);
      }
    }
    #pragma unroll
    for (int r = 0; r < 4; r++){
      tm[r] = fmaxf(tm[r], __shfl_xor(tm[r], 1));
      tm[r] = fmaxf(tm[r], __shfl_xor(tm[r], 2));
      tm[r] = fmaxf(tm[r], __shfl_xor(tm[r], 4));
      tm[r] = fmaxf(tm[r], __shfl_xor(tm[r], 8));
    }
    float corr[4];
    #pragma unroll
    for (int r = 0; r < 4; r++){
      float mn = fmaxf(mrun[r], tm[r]);
      corr[r] = __expf(mrun[r] - mn);
      mrun[r] = mn;
    }
    #pragma unroll
    for (int r = 0; r < 4; r++){
      float sum = 0.f;
      #pragma unroll
      for (int n = 0; n < 4; n++){
        float pv = __expf(p[n][r] - mrun[r]);
        p[n][r] = pv;
        sum += pv;
      }
      sum += __shfl_xor(sum, 1);
      sum += __shfl_xor(sum, 2);
      sum += __shfl_xor(sum, 4);
      sum += __shfl_xor(sum, 8);
      lrun[r] = lrun[r]*corr[r] + sum;
    }
    #pragma unroll
    for (int nn = 0; nn < 8; nn++)
      #pragma unroll
      for (int r = 0; r < 4; r++)
        acco[nn][r] *= corr[r];

    // P -> LDS (bf16, chunk-swizzled), per-wave private region
    #pragma unroll
    for (int n = 0; n < 4; n++){
      const int colb = n*16 + l15;
      #pragma unroll
      for (int r = 0; r < 4; r++){
        const int row = lh*4 + r;
        const int off = row*64 + (((colb>>3) ^ (row&7))<<3) + (colb&7);
        pwh[off] = f2bf(p[n][r]);
      }
    }
    asm volatile("" ::: "memory");  // order LDS P writes before vector re-reads

    // O += P V  (single term)
    #pragma unroll
    for (int kt2 = 0; kt2 < 2; kt2++){
      const int ac = (kt2*4 + lh) ^ (l15 & 7);
      bf16x8 afh = *(const bf16x8*)(pwh + l15*64 + ac*8);
      #pragma unroll
      for (int n = 0; n < 8; n++){
        const int d = n*16 + l15;
        const int c = (kt2*4 + lh) ^ (d & 7);
        bf16x8 bvh = *(const bf16x8*)(Vhs + d*64 + c*8);
        acco[n] = MFMA_B16(afh, bvh, acco[n]);
      }
    }
  }

  #pragma unroll
  for (int n = 0; n < 8; n++){
    const int col = h*128 + n*16 + l15;
    #pragma unroll
    for (int r = 0; r < 4; r++){
      atth[(size_t)(qrow0+r)*2048 + col] = f2bf(acco[n][r] / lrun[r]);
    }
  }
}

// ---------- LayerNorm (two-pass, fp32); WSPLIT=1 also writes bf16 hi/lo planes ----------
template<int WSPLIT>
__global__ __launch_bounds__(256) void ln_k(
    const float* __restrict__ in, float* __restrict__ outf,
    u16* __restrict__ outh, u16* __restrict__ outl,
    const float* __restrict__ gptr, const float* __restrict__ beta)
{
  const int tid = threadIdx.x;
  const int lane = tid & 63;
  const int w = tid >> 6;
  const int row = blockIdx.x;
  const float4* xr = (const float4*)(in + (size_t)row*2048);
  float4 a = xr[tid];
  float4 b = xr[tid + 256];
  float s = a.x+a.y+a.z+a.w + b.x+b.y+b.z+b.w;
  #pragma unroll
  for (int off = 32; off; off >>= 1) s += __shfl_xor(s, off);
  __shared__ float red[8];
  if (lane == 0) red[w] = s;
  __syncthreads();
  const float mean = (red[0]+red[1]+red[2]+red[3]) * (1.0f/2048.0f);
  float q =
    (a.x-mean)*(a.x-mean) + (a.y-mean)*(a.y-mean) + (a.z-mean)*(a.z-mean) + (a.w-mean)*(a.w-mean) +
    (b.x-mean)*(b.x-mean) + (b.y-mean)*(b.y-mean) + (b.z-mean)*(b.z-mean) + (b.w-mean)*(b.w-mean);
  #pragma unroll
  for (int off = 32; off; off >>= 1) q += __shfl_xor(q, off);
  if (lane == 0) red[4 + w] = q;
  __syncthreads();
  const float var = (red[4]+red[5]+red[6]+red[7]) * (1.0f/2048.0f);
  const float sc = rsqrtf(var + 1e-5f) * gptr[0];
  const float4 be0 = ((const float4*)beta)[tid];
  const float4 be1 = ((const float4*)beta)[tid + 256];
  float4 o0, o1;
  o0.x = (a.x-mean)*sc + be0.x; o0.y = (a.y-mean)*sc + be0.y;
  o0.z = (a.z-mean)*sc + be0.z; o0.w = (a.w-mean)*sc + be0.w;
  o1.x = (b.x-mean)*sc + be1.x; o1.y = (b.y-mean)*sc + be1.y;
  o1.z = (b.z-mean)*sc + be1.z; o1.w = (b.w-mean)*sc + be1.w;
  float4* orow = (float4*)(outf + (size_t)row*2048);
  orow[tid] = o0; orow[tid+256] = o1;
  if (WSPLIT){
    ushort4 h0 = make_ushort4(f2bf(o0.x), f2bf(o0.y), f2bf(o0.z), f2bf(o0.w));
    ushort4 h1 = make_ushort4(f2bf(o1.x), f2bf(o1.y), f2bf(o1.z), f2bf(o1.w));
    ushort4 L0 = make_ushort4(f2bf(o0.x - bf2f(h0.x)), f2bf(o0.y - bf2f(h0.y)),
                              f2bf(o0.z - bf2f(h0.z)), f2bf(o0.w - bf2f(h0.w)));
    ushort4 L1 = make_ushort4(f2bf(o1.x - bf2f(h1.x)), f2bf(o1.y - bf2f(h1.y)),
                              f2bf(o1.z - bf2f(h1.z)), f2bf(o1.w - bf2f(h1.w)));
    ushort4* hrow = (ushort4*)(outh + (size_t)row*2048);
    ushort4* lrow = (ushort4*)(outl + (size_t)row*2048);
    hrow[tid] = h0; hrow[tid+256] = h1;
    lrow[tid] = L0; lrow[tid+256] = L1;
  }
}

// ---------- launch ----------
extern "C" void kernel_launch(void* const* d_in, const int* in_sizes, int n_in,
                              void* d_out, int out_size, void* d_ws, size_t ws_size,
                              hipStream_t stream)
{
  const float* x   = (const float*)d_in[0];
  const float* WQ  = (const float*)d_in[1];
  const float* WK  = (const float*)d_in[2];
  const float* WV  = (const float*)d_in[3];
  const float* WP  = (const float*)d_in[4];
  const float* W1  = (const float*)d_in[5];
  const float* b1  = (const float*)d_in[6];
  const float* W2  = (const float*)d_in[7];
  const float* b2  = (const float*)d_in[8];
  const float* gam = (const float*)d_in[9];
  const float* bet = (const float*)d_in[10];
  float* out = (float*)d_out;
  (void)in_sizes; (void)n_in; (void)out_size; (void)ws_size;

  const size_t NP = 2048ull*2048;          // elements per 2048x2048 plane
  char* pR1 = (char*)d_ws;                 // 64 MiB: weight hi plane @0, lo plane @32MiB
  char* pR2 = pR1 + (64ull<<20);           // 32 MiB: xh,xl | later a1 (2048x8192)
  char* pR3 = pR2 + (32ull<<20);           // 48 MiB: q/k hi-lo + vT | later Hh,Hl
  char* pR4 = pR3 + (48ull<<20);           // 16 MiB: ATTh | later H1 (fp32)
  char* pR5 = pR4 + (16ull<<20);           // 16 MiB: PR (fp32)

  u16* Wh   = (u16*)pR1;
  u16* Wl   = (u16*)(pR1 + (32ull<<20));
  u16* xh   = (u16*)pR2;
  u16* xl   = xh + NP;
  u16* a1   = (u16*)pR2;                   // 2048x8192 bf16 (after xh/xl dead)
  u16* qh_  = (u16*)pR3;
  u16* ql_  = qh_ + NP;
  u16* kh_  = ql_ + NP;
  u16* kl_  = kh_ + NP;
  u16* vT_  = kl_ + NP;
  u16* Hh   = (u16*)pR3;                   // after attn done
  u16* Hl   = Hh + NP;
  u16* ATTh = (u16*)pR4;
  float* H1 = (float*)pR4;                 // after pool done
  float* PR = (float*)pR5;

  // 1) pack x and W_QKV into hi/lo planes
  pack_x2 <<<2048*2048/256, 256, 0, stream>>>(x, xh, xl);
  pack_qkv2<<<dim3(256,16,3), 256, 0, stream>>>(WQ, WK, WV, Wh, Wl);
  // 2) QKV projection, 3-term split (M=2048, N=6144, K=2048)
  gemm_bt<3,0><<<768, 256, 0, stream>>>(xh, xl, Wh, Wl, nullptr, nullptr, nullptr, nullptr,
                                        qh_, ql_, kh_, kl_, vT_, 2048, 6144, 2048);
  // 3) causal flash attention -> ATTh (bf16 [n][h*128+d])
  attn_k<<<dim3(32,16), 256, 0, stream>>>(qh_, ql_, kh_, kl_, vT_, ATTh);
  // 4) pool GEMM (1-term) + residual: PR = x + ATT @ W_Pool
  tpack2<<<dim3(64,64), 256, 0, stream>>>(WP, Wh, Wl, 2048, 2048);
  gemm_bt<1,1><<<256, 256, 0, stream>>>(ATTh, nullptr, Wh, nullptr, PR, nullptr, nullptr, x,
                                        nullptr, nullptr, nullptr, nullptr, nullptr,
                                        2048, 2048, 2048);
  // 5) LN1 -> H1 (fp32) + Hh/Hl planes
  ln_k<1><<<2048, 256, 0, stream>>>(PR, H1, Hh, Hl, gam, bet);
  // 6) FFN1 (1-term): a1 = relu(H @ W1 + b1) -> bf16
  tpack2<<<dim3(256,64), 256, 0, stream>>>(W1, Wh, Wl, 2048, 8192);
  gemm_bt<1,2><<<1024, 256, 0, stream>>>(Hh, nullptr, Wh, nullptr, nullptr, a1, b1, nullptr,
                                         nullptr, nullptr, nullptr, nullptr, nullptr,
                                         2048, 8192, 2048);
  // 7) FFN2 (2-term: a1*W2h + a1*W2l) + residual: PR = H1 + a1 @ W2 + b2
  tpack2<<<dim3(64,256), 256, 0, stream>>>(W2, Wh, Wl, 8192, 2048);
  gemm_bt<2,3><<<256, 256, 0, stream>>>(a1, nullptr, Wh, Wl, PR, nullptr, b2, H1,
                                        nullptr, nullptr, nullptr, nullptr, nullptr,
                                        2048, 2048, 8192);
  // 8) LN2 -> out
  ln_k<0><<<2048, 256, 0, stream>>>(PR, out, nullptr, nullptr, gam, bet);
}

// Round 4
// 777.673 us; speedup vs baseline: 1.0061x; 1.0061x over previous
//
#include <hip/hip_runtime.h>

// ---------- common ----------
typedef unsigned short u16;
typedef unsigned int   u32;
typedef __attribute__((ext_vector_type(4))) float f32x4;
typedef __attribute__((ext_vector_type(8))) short bf16x8;

#define MFMA_B16(a,b,c) __builtin_amdgcn_mfma_f32_16x16x32_bf16((a),(b),(c),0,0,0)

__device__ __forceinline__ u16 f2bf(float f){
  u32 u = __builtin_bit_cast(u32, f);
  u32 r = (u + 0x7FFFu + ((u >> 16) & 1u)) >> 16;   // round-to-nearest-even
  return (u16)r;
}
__device__ __forceinline__ float bf2f(u16 h){
  u32 u = ((u32)h) << 16;
  return __builtin_bit_cast(float, u);
}
// async global->LDS, 16B per lane; LDS dest is wave-uniform base (+lane*16 implicit)
__device__ __forceinline__ void gload16(const void* g, void* l){
  __builtin_amdgcn_global_load_lds((const __attribute__((address_space(1))) void*)g,
                                   (__attribute__((address_space(3))) void*)l, 16, 0, 0);
}

// ---------- packing kernels ----------
// x (N,E) f32 -> xh, xl bf16 planes
__global__ __launch_bounds__(256) void pack_x2(const float* __restrict__ x,
                                               u16* __restrict__ xh, u16* __restrict__ xl){
  const int i = blockIdx.x*256 + threadIdx.x;
  const float v = x[i];
  const u16 hi = f2bf(v);
  xh[i] = hi;
  xl[i] = f2bf(v - bf2f(hi));
}

// W_Q/K/V (H,E,D) f32 -> BT planes [6144][2048] (row j = t*2048+h*128+d, col k=e), hi & lo
__global__ __launch_bounds__(256) void pack_qkv2(const float* __restrict__ WQ, const float* __restrict__ WK,
                                                 const float* __restrict__ WV,
                                                 u16* __restrict__ outh, u16* __restrict__ outl){
  __shared__ float t32[32][33];
  const int tid = threadIdx.x;
  const int tx = tid & 31, ty = tid >> 5;
  const int et = blockIdx.x >> 2, dt = blockIdx.x & 3;   // e-tile (64), d-tile (4)
  const int hh = blockIdx.y, tt = blockIdx.z;
  const float* W = (tt == 0 ? WQ : (tt == 1 ? WK : WV)) + (size_t)hh*2048*128;
  #pragma unroll
  for (int i = 0; i < 4; i++)
    t32[ty + i*8][tx] = W[(size_t)(et*32 + ty + i*8)*128 + dt*32 + tx];
  __syncthreads();
  const int j0 = tt*2048 + hh*128 + dt*32;
  #pragma unroll
  for (int i = 0; i < 4; i++){
    const float v = t32[tx][ty + i*8];
    const u16 hi = f2bf(v);
    const u16 lo = f2bf(v - bf2f(hi));
    const size_t idx = (size_t)(j0 + ty + i*8)*2048 + (et*32 + tx);
    outh[idx] = hi; outl[idx] = lo;
  }
}

// in (R,C) f32 -> outh/outl (C,R) bf16 hi/lo planes (transpose + split)
__global__ __launch_bounds__(256) void tpack2(const float* __restrict__ in,
                                              u16* __restrict__ outh, u16* __restrict__ outl,
                                              int R, int C){
  __shared__ float t32[32][33];
  const int tid = threadIdx.x;
  const int tx = tid & 31, ty = tid >> 5;
  const int c0 = blockIdx.x*32, r0 = blockIdx.y*32;
  #pragma unroll
  for (int i = 0; i < 4; i++)
    t32[ty + i*8][tx] = in[(size_t)(r0 + ty + i*8)*C + c0 + tx];
  __syncthreads();
  #pragma unroll
  for (int i = 0; i < 4; i++){
    const float v = t32[tx][ty + i*8];
    const u16 hi = f2bf(v);
    const u16 lo = f2bf(v - bf2f(hi));
    const size_t idx = (size_t)(c0 + ty + i*8)*R + r0 + tx;
    outh[idx] = hi; outl[idx] = lo;
  }
}

// ---------- GEMM: C(M,N) = A(M,K)*BT(N,K)^T with hi/lo plane phases ----------
// Double-buffered LDS + counted vmcnt (T3-minimum 2-phase schedule).
// NS=1: Ah*Bh. NS=2: Ah*Bh + Ah*Bl. NS=3: Ah*Bh + Ah*Bl + Al*Bh.
// EPI 0: QKV split-write   1: f32 + res    2: bias+relu -> bf16    3: bias + res -> f32
template<int NS, int EPI>
__global__ __launch_bounds__(256) void gemm_bt(
    const u16* __restrict__ Ah, const u16* __restrict__ Al,
    const u16* __restrict__ Bh, const u16* __restrict__ Bl,
    float* __restrict__ outf, u16* __restrict__ outb,
    const float* __restrict__ bias, const float* __restrict__ res,
    u16* __restrict__ qh, u16* __restrict__ ql,
    u16* __restrict__ kh, u16* __restrict__ kl,
    u16* __restrict__ vTh,
    int M, int N, int K)
{
  __shared__ u16 As[2][128*64];
  __shared__ u16 Bs[2][128*64];
  const int tid = threadIdx.x;
  const int lane = tid & 63;
  const int w = tid >> 6;
  const int l15 = lane & 15, lh = lane >> 4;
  const int nbx = N >> 7;
  // XCD-bijective swizzle (grid always divisible by 8 here)
  const int bsw = ((int)blockIdx.x & 7)*((int)gridDim.x >> 3) + ((int)blockIdx.x >> 3);
  const int bx = bsw % nbx, by = bsw / nbx;
  const int m0 = by << 7, n0 = bx << 7;
  const int wm = (w >> 1) << 6, wn = (w & 1) << 6;

  f32x4 acc[4][4] = {};

  const int KV = NS * K;
  const int NT = KV >> 6;

  // stage one 128x64 A tile + 128x64 B tile into buffer `buf` (8 gload16/thread)
  auto stage = [&](int buf, int k0v){
    const u16* Ap; const u16* Bp; int kk;
    if (NS == 1){ Ap = Ah; Bp = Bh; kk = k0v; }
    else if (NS == 2){
      if (k0v < K){ Ap = Ah; Bp = Bh; kk = k0v; }
      else        { Ap = Ah; Bp = Bl; kk = k0v - K; }
    } else {
      if (k0v < K)        { Ap = Ah; Bp = Bh; kk = k0v; }
      else if (k0v < 2*K) { Ap = Ah; Bp = Bl; kk = k0v - K; }
      else                { Ap = Al; Bp = Bh; kk = k0v - 2*K; }
    }
    u16* Asb = &As[buf][0];
    u16* Bsb = &Bs[buf][0];
    #pragma unroll
    for (int q = 0; q < 4; q++){          // A tile 128 rows x 64 cols, chunk-swizzled source
      int s = q*256 + tid;
      int row = s >> 3, cc = (s & 7) ^ (row & 7);
      gload16(Ap + (size_t)(m0+row)*K + kk + cc*8, Asb + (q*256 + (tid & 192))*8);
    }
    #pragma unroll
    for (int q = 0; q < 4; q++){          // B tile 128 rows x 64 cols
      int s = q*256 + tid;
      int row = s >> 3, cc = (s & 7) ^ (row & 7);
      gload16(Bp + (size_t)(n0+row)*K + kk + cc*8, Bsb + (q*256 + (tid & 192))*8);
    }
  };

  stage(0, 0);
  for (int t = 0; t < NT; ++t){
    const int cur = t & 1;
    if (t + 1 < NT){
      stage(cur ^ 1, (t + 1) << 6);
      asm volatile("s_waitcnt vmcnt(8)" ::: "memory");   // tile t done; t+1 in flight
    } else {
      asm volatile("s_waitcnt vmcnt(0)" ::: "memory");
    }
    __builtin_amdgcn_s_barrier();
    asm volatile("" ::: "memory");

    const u16* Asb = &As[cur][0];
    const u16* Bsb = &Bs[cur][0];
    #pragma unroll
    for (int kt = 0; kt < 2; kt++){
      bf16x8 af[4], bfr[4];
      #pragma unroll
      for (int m = 0; m < 4; m++){
        int row = wm + m*16 + l15;
        int c = (kt*4 + lh) ^ (row & 7);
        af[m] = *(const bf16x8*)(Asb + row*64 + c*8);
      }
      #pragma unroll
      for (int n = 0; n < 4; n++){
        int row = wn + n*16 + l15;
        int c = (kt*4 + lh) ^ (row & 7);
        bfr[n] = *(const bf16x8*)(Bsb + row*64 + c*8);
      }
      #pragma unroll
      for (int m = 0; m < 4; m++)
        #pragma unroll
        for (int n = 0; n < 4; n++)
          acc[m][n] = MFMA_B16(af[m], bfr[n], acc[m][n]);
    }
    asm volatile("" ::: "memory");
    __builtin_amdgcn_s_barrier();          // all reads of buf `cur` done before next overwrite
    asm volatile("" ::: "memory");
  }

  // epilogue: C/D layout col=lane&15, row=(lane>>4)*4+r
  #pragma unroll
  for (int m = 0; m < 4; m++){
    #pragma unroll
    for (int n = 0; n < 4; n++){
      const int rbase = m0 + wm + m*16 + lh*4;
      const int col = n0 + wn + n*16 + l15;
      if (EPI == 0){
        const int plane = col >> 11;      // 0=Q 1=K 2=V
        const int cj = col & 2047;
        if (plane == 2){
          ushort4 h4 = make_ushort4(f2bf(acc[m][n][0]), f2bf(acc[m][n][1]),
                                    f2bf(acc[m][n][2]), f2bf(acc[m][n][3]));
          *(ushort4*)(vTh + (size_t)cj*2048 + rbase) = h4;   // V transposed [hd][n]
        } else {
          u16* hp = (plane == 0) ? qh : kh;
          u16* lp = (plane == 0) ? ql : kl;
          #pragma unroll
          for (int r = 0; r < 4; r++){
            float v = acc[m][n][r];
            u16 hi = f2bf(v);
            u16 lo = f2bf(v - bf2f(hi));
            hp[(size_t)(rbase+r)*2048 + cj] = hi;
            lp[(size_t)(rbase+r)*2048 + cj] = lo;
          }
        }
      } else if (EPI == 1){
        #pragma unroll
        for (int r = 0; r < 4; r++){
          size_t idx = (size_t)(rbase+r)*N + col;
          outf[idx] = acc[m][n][r] + res[idx];
        }
      } else if (EPI == 2){
        const float b = bias[col];
        #pragma unroll
        for (int r = 0; r < 4; r++){
          float v = acc[m][n][r] + b;
          outb[(size_t)(rbase+r)*N + col] = f2bf(v > 0.f ? v : 0.f);
        }
      } else {
        const float b = bias[col];
        #pragma unroll
        for (int r = 0; r < 4; r++){
          size_t idx = (size_t)(rbase+r)*N + col;
          outf[idx] = acc[m][n][r] + b + res[idx];
        }
      }
    }
  }
}

// ---------- flash attention (causal), 4 waves x 16 q-rows, KV tile 64 ----------
// Q,K hi/lo (3-term QK^T); V, P single bf16 (1-term PV); out single plane
__global__ __launch_bounds__(256) void attn_k(
    const u16* __restrict__ qh, const u16* __restrict__ ql,
    const u16* __restrict__ kh, const u16* __restrict__ kl,
    const u16* __restrict__ vT, u16* __restrict__ atth)
{
  __shared__ u16 Khs[64*128];
  __shared__ u16 Kls[64*128];
  __shared__ u16 Vhs[128*64];
  __shared__ u16 Phs[4*16*64];

  const int tid = threadIdx.x;
  const int lane = tid & 63;
  const int w = tid >> 6;
  const int l15 = lane & 15, lh = lane >> 4;
  const int h = blockIdx.y;
  const int qb = blockIdx.x;
  const int qbase = qb << 6;
  const float scale = 0.088388347648318447f;  // 1/sqrt(128)

  bf16x8 qfh[4], qfl[4];
  {
    const int qrow = qbase + w*16 + l15;
    const u16* ph = qh + (size_t)qrow*2048 + h*128 + lh*8;
    const u16* pl = ql + (size_t)qrow*2048 + h*128 + lh*8;
    #pragma unroll
    for (int kt = 0; kt < 4; kt++){
      qfh[kt] = *(const bf16x8*)(ph + kt*32);
      qfl[kt] = *(const bf16x8*)(pl + kt*32);
    }
  }

  f32x4 acco[8] = {};
  float mrun[4] = {-1e30f,-1e30f,-1e30f,-1e30f};
  float lrun[4] = {0.f,0.f,0.f,0.f};
  const int qrow0 = qbase + w*16 + lh*4;
  u16* pwh = Phs + w*1024;

  const int nkv = qb + 1;
  for (int kvt = 0; kvt < nkv; kvt++){
    const int kv0 = kvt << 6;
    __syncthreads();
    // K tiles are [64 rows][128 cols] = 16 chunks/row: row = s>>4, chunk = s&15
    #pragma unroll
    for (int q = 0; q < 4; q++){
      int s = q*256 + tid;
      int row = s >> 4, c = (s & 15) ^ (row & 7);
      gload16(kh + (size_t)(kv0+row)*2048 + h*128 + c*8, Khs + (q*256 + (tid & 192))*8);
    }
    #pragma unroll
    for (int q = 0; q < 4; q++){
      int s = q*256 + tid;
      int row = s >> 4, c = (s & 15) ^ (row & 7);
      gload16(kl + (size_t)(kv0+row)*2048 + h*128 + c*8, Kls + (q*256 + (tid & 192))*8);
    }
    // V tile is [128 rows][64 cols] = 8 chunks/row: row = s>>3, chunk = s&7
    #pragma unroll
    for (int q = 0; q < 4; q++){
      int s = q*256 + tid;
      int d = s >> 3, c = (s & 7) ^ (d & 7);
      gload16(vT + (size_t)(h*128+d)*2048 + kv0 + c*8, Vhs + (q*256 + (tid & 192))*8);
    }
    asm volatile("s_waitcnt vmcnt(0)" ::: "memory");
    __syncthreads();

    // S = Q K^T (split-2: hi*hi + hi*lo + lo*hi)
    f32x4 sac[4] = {};
    __builtin_amdgcn_s_setprio(1);
    #pragma unroll
    for (int n = 0; n < 4; n++){
      const int kvr = n*16 + l15;
      const u16* kb  = Khs + kvr*128;
      const u16* klb = Kls + kvr*128;
      const int sw = kvr & 7;
      #pragma unroll
      for (int kt = 0; kt < 4; kt++){
        const int c = (kt*4 + lh) ^ sw;
        bf16x8 bh = *(const bf16x8*)(kb + c*8);
        bf16x8 bl = *(const bf16x8*)(klb + c*8);
        sac[n] = MFMA_B16(qfh[kt], bh, sac[n]);
        sac[n] = MFMA_B16(qfh[kt], bl, sac[n]);
        sac[n] = MFMA_B16(qfl[kt], bh, sac[n]);
      }
    }
    __builtin_amdgcn_s_setprio(0);

    // online softmax (fp32)
    float p[4][4];
    float tm[4] = {-1e30f,-1e30f,-1e30f,-1e30f};
    #pragma unroll
    for (int n = 0; n < 4; n++){
      const int kvg = kv0 + n*16 + l15;
      #pragma unroll
      for (int r = 0; r < 4; r++){
        float s = sac[n][r] * scale;
        if (kvg > qrow0 + r) s = -1e30f;   // causal mask
        p[n][r] = s;
        tm[r] = fmaxf(tm[r], s);
      }
    }
    #pragma unroll
    for (int r = 0; r < 4; r++){
      tm[r] = fmaxf(tm[r], __shfl_xor(tm[r], 1));
      tm[r] = fmaxf(tm[r], __shfl_xor(tm[r], 2));
      tm[r] = fmaxf(tm[r], __shfl_xor(tm[r], 4));
      tm[r] = fmaxf(tm[r], __shfl_xor(tm[r], 8));
    }
    float corr[4];
    #pragma unroll
    for (int r = 0; r < 4; r++){
      float mn = fmaxf(mrun[r], tm[r]);
      corr[r] = __expf(mrun[r] - mn);
      mrun[r] = mn;
    }
    #pragma unroll
    for (int r = 0; r < 4; r++){
      float sum = 0.f;
      #pragma unroll
      for (int n = 0; n < 4; n++){
        float pv = __expf(p[n][r] - mrun[r]);
        p[n][r] = pv;
        sum += pv;
      }
      sum += __shfl_xor(sum, 1);
      sum += __shfl_xor(sum, 2);
      sum += __shfl_xor(sum, 4);
      sum += __shfl_xor(sum, 8);
      lrun[r] = lrun[r]*corr[r] + sum;
    }
    #pragma unroll
    for (int nn = 0; nn < 8; nn++)
      #pragma unroll
      for (int r = 0; r < 4; r++)
        acco[nn][r] *= corr[r];

    // P -> LDS (bf16, chunk-swizzled), per-wave private region
    #pragma unroll
    for (int n = 0; n < 4; n++){
      const int colb = n*16 + l15;
      #pragma unroll
      for (int r = 0; r < 4; r++){
        const int row = lh*4 + r;
        const int off = row*64 + (((colb>>3) ^ (row&7))<<3) + (colb&7);
        pwh[off] = f2bf(p[n][r]);
      }
    }
    asm volatile("" ::: "memory");  // order LDS P writes before vector re-reads

    // O += P V  (single term)
    __builtin_amdgcn_s_setprio(1);
    #pragma unroll
    for (int kt2 = 0; kt2 < 2; kt2++){
      const int ac = (kt2*4 + lh) ^ (l15 & 7);
      bf16x8 afh = *(const bf16x8*)(pwh + l15*64 + ac*8);
      #pragma unroll
      for (int n = 0; n < 8; n++){
        const int d = n*16 + l15;
        const int c = (kt2*4 + lh) ^ (d & 7);
        bf16x8 bvh = *(const bf16x8*)(Vhs + d*64 + c*8);
        acco[n] = MFMA_B16(afh, bvh, acco[n]);
      }
    }
    __builtin_amdgcn_s_setprio(0);
  }

  #pragma unroll
  for (int n = 0; n < 8; n++){
    const int col = h*128 + n*16 + l15;
    #pragma unroll
    for (int r = 0; r < 4; r++){
      atth[(size_t)(qrow0+r)*2048 + col] = f2bf(acco[n][r] / lrun[r]);
    }
  }
}

// ---------- LayerNorm (two-pass, fp32); WSPLIT=1 also writes bf16 hi/lo planes ----------
template<int WSPLIT>
__global__ __launch_bounds__(256) void ln_k(
    const float* __restrict__ in, float* __restrict__ outf,
    u16* __restrict__ outh, u16* __restrict__ outl,
    const float* __restrict__ gptr, const float* __restrict__ beta)
{
  const int tid = threadIdx.x;
  const int lane = tid & 63;
  const int w = tid >> 6;
  const int row = blockIdx.x;
  const float4* xr = (const float4*)(in + (size_t)row*2048);
  float4 a = xr[tid];
  float4 b = xr[tid + 256];
  float s = a.x+a.y+a.z+a.w + b.x+b.y+b.z+b.w;
  #pragma unroll
  for (int off = 32; off; off >>= 1) s += __shfl_xor(s, off);
  __shared__ float red[8];
  if (lane == 0) red[w] = s;
  __syncthreads();
  const float mean = (red[0]+red[1]+red[2]+red[3]) * (1.0f/2048.0f);
  float q =
    (a.x-mean)*(a.x-mean) + (a.y-mean)*(a.y-mean) + (a.z-mean)*(a.z-mean) + (a.w-mean)*(a.w-mean) +
    (b.x-mean)*(b.x-mean) + (b.y-mean)*(b.y-mean) + (b.z-mean)*(b.z-mean) + (b.w-mean)*(b.w-mean);
  #pragma unroll
  for (int off = 32; off; off >>= 1) q += __shfl_xor(q, off);
  if (lane == 0) red[4 + w] = q;
  __syncthreads();
  const float var = (red[4]+red[5]+red[6]+red[7]) * (1.0f/2048.0f);
  const float sc = rsqrtf(var + 1e-5f) * gptr[0];
  const float4 be0 = ((const float4*)beta)[tid];
  const float4 be1 = ((const float4*)beta)[tid + 256];
  float4 o0, o1;
  o0.x = (a.x-mean)*sc + be0.x; o0.y = (a.y-mean)*sc + be0.y;
  o0.z = (a.z-mean)*sc + be0.z; o0.w = (a.w-mean)*sc + be0.w;
  o1.x = (b.x-mean)*sc + be1.x; o1.y = (b.y-mean)*sc + be1.y;
  o1.z = (b.z-mean)*sc + be1.z; o1.w = (b.w-mean)*sc + be1.w;
  float4* orow = (float4*)(outf + (size_t)row*2048);
  orow[tid] = o0; orow[tid+256] = o1;
  if (WSPLIT){
    ushort4 h0 = make_ushort4(f2bf(o0.x), f2bf(o0.y), f2bf(o0.z), f2bf(o0.w));
    ushort4 h1 = make_ushort4(f2bf(o1.x), f2bf(o1.y), f2bf(o1.z), f2bf(o1.w));
    ushort4 L0 = make_ushort4(f2bf(o0.x - bf2f(h0.x)), f2bf(o0.y - bf2f(h0.y)),
                              f2bf(o0.z - bf2f(h0.z)), f2bf(o0.w - bf2f(h0.w)));
    ushort4 L1 = make_ushort4(f2bf(o1.x - bf2f(h1.x)), f2bf(o1.y - bf2f(h1.y)),
                              f2bf(o1.z - bf2f(h1.z)), f2bf(o1.w - bf2f(h1.w)));
    ushort4* hrow = (ushort4*)(outh + (size_t)row*2048);
    ushort4* lrow = (ushort4*)(outl + (size_t)row*2048);
    hrow[tid] = h0; hrow[tid+256] = h1;
    lrow[tid] = L0; lrow[tid+256] = L1;
  }
}

// ---------- launch ----------
extern "C" void kernel_launch(void* const* d_in, const int* in_sizes, int n_in,
                              void* d_out, int out_size, void* d_ws, size_t ws_size,
                              hipStream_t stream)
{
  const float* x   = (const float*)d_in[0];
  const float* WQ  = (const float*)d_in[1];
  const float* WK  = (const float*)d_in[2];
  const float* WV  = (const float*)d_in[3];
  const float* WP  = (const float*)d_in[4];
  const float* W1  = (const float*)d_in[5];
  const float* b1  = (const float*)d_in[6];
  const float* W2  = (const float*)d_in[7];
  const float* b2  = (const float*)d_in[8];
  const float* gam = (const float*)d_in[9];
  const float* bet = (const float*)d_in[10];
  float* out = (float*)d_out;
  (void)in_sizes; (void)n_in; (void)out_size; (void)ws_size;

  const size_t NP = 2048ull*2048;          // elements per 2048x2048 plane
  char* pR1 = (char*)d_ws;                 // 64 MiB: weight hi plane @0, lo plane @32MiB
  char* pR2 = pR1 + (64ull<<20);           // 32 MiB: xh,xl | later a1 (2048x8192)
  char* pR3 = pR2 + (32ull<<20);           // 48 MiB: q/k hi-lo + vT | later Hh,Hl
  char* pR4 = pR3 + (48ull<<20);           // 16 MiB: ATTh | later H1 (fp32)
  char* pR5 = pR4 + (16ull<<20);           // 16 MiB: PR (fp32)

  u16* Wh   = (u16*)pR1;
  u16* Wl   = (u16*)(pR1 + (32ull<<20));
  u16* xh   = (u16*)pR2;
  u16* xl   = xh + NP;
  u16* a1   = (u16*)pR2;                   // 2048x8192 bf16 (after xh/xl dead)
  u16* qh_  = (u16*)pR3;
  u16* ql_  = qh_ + NP;
  u16* kh_  = ql_ + NP;
  u16* kl_  = kh_ + NP;
  u16* vT_  = kl_ + NP;
  u16* Hh   = (u16*)pR3;                   // after attn done
  u16* Hl   = Hh + NP;
  u16* ATTh = (u16*)pR4;
  float* H1 = (float*)pR4;                 // after pool done
  float* PR = (float*)pR5;

  // 1) pack x and W_QKV into hi/lo planes
  pack_x2 <<<2048*2048/256, 256, 0, stream>>>(x, xh, xl);
  pack_qkv2<<<dim3(256,16,3), 256, 0, stream>>>(WQ, WK, WV, Wh, Wl);
  // 2) QKV projection, 3-term split (M=2048, N=6144, K=2048)
  gemm_bt<3,0><<<768, 256, 0, stream>>>(xh, xl, Wh, Wl, nullptr, nullptr, nullptr, nullptr,
                                        qh_, ql_, kh_, kl_, vT_, 2048, 6144, 2048);
  // 3) causal flash attention -> ATTh (bf16 [n][h*128+d])
  attn_k<<<dim3(32,16), 256, 0, stream>>>(qh_, ql_, kh_, kl_, vT_, ATTh);
  // 4) pool GEMM (1-term) + residual: PR = x + ATT @ W_Pool
  tpack2<<<dim3(64,64), 256, 0, stream>>>(WP, Wh, Wl, 2048, 2048);
  gemm_bt<1,1><<<256, 256, 0, stream>>>(ATTh, nullptr, Wh, nullptr, PR, nullptr, nullptr, x,
                                        nullptr, nullptr, nullptr, nullptr, nullptr,
                                        2048, 2048, 2048);
  // 5) LN1 -> H1 (fp32) + Hh/Hl planes
  ln_k<1><<<2048, 256, 0, stream>>>(PR, H1, Hh, Hl, gam, bet);
  // 6) FFN1 (1-term): a1 = relu(H @ W1 + b1) -> bf16
  tpack2<<<dim3(256,64), 256, 0, stream>>>(W1, Wh, Wl, 2048, 8192);
  gemm_bt<1,2><<<1024, 256, 0, stream>>>(Hh, nullptr, Wh, nullptr, nullptr, a1, b1, nullptr,
                                         nullptr, nullptr, nullptr, nullptr, nullptr,
                                         2048, 8192, 2048);
  // 7) FFN2 (2-term: a1*W2h + a1*W2l) + residual: PR = H1 + a1 @ W2 + b2
  tpack2<<<dim3(64,256), 256, 0, stream>>>(W2, Wh, Wl, 8192, 2048);
  gemm_bt<2,3><<<256, 256, 0, stream>>>(a1, nullptr, Wh, Wl, PR, nullptr, b2, H1,
                                        nullptr, nullptr, nullptr, nullptr, nullptr,
                                        2048, 2048, 8192);
  // 8) LN2 -> out
  ln_k<0><<<2048, 256, 0, stream>>>(PR, out, nullptr, nullptr, gam, bet);
}

// Round 5
// 643.335 us; speedup vs baseline: 1.2162x; 1.2088x over previous
//
#include <hip/hip_runtime.h>

// ---------- common ----------
typedef unsigned short u16;
typedef unsigned int   u32;
typedef __attribute__((ext_vector_type(4))) float f32x4;
typedef __attribute__((ext_vector_type(8))) short bf16x8;

#define MFMA_B16(a,b,c) __builtin_amdgcn_mfma_f32_16x16x32_bf16((a),(b),(c),0,0,0)

__device__ __forceinline__ u16 f2bf(float f){
  u32 u = __builtin_bit_cast(u32, f);
  u32 r = (u + 0x7FFFu + ((u >> 16) & 1u)) >> 16;   // round-to-nearest-even
  return (u16)r;
}
__device__ __forceinline__ float bf2f(u16 h){
  u32 u = ((u32)h) << 16;
  return __builtin_bit_cast(float, u);
}
// async global->LDS, 16B per lane; LDS dest is wave-uniform base (+lane*16 implicit)
__device__ __forceinline__ void gload16(const void* g, void* l){
  __builtin_amdgcn_global_load_lds((const __attribute__((address_space(1))) void*)g,
                                   (__attribute__((address_space(3))) void*)l, 16, 0, 0);
}

// ---------- packing kernels ----------
__global__ __launch_bounds__(256) void pack_x2(const float* __restrict__ x,
                                               u16* __restrict__ xh, u16* __restrict__ xl){
  const int i = blockIdx.x*256 + threadIdx.x;
  const float v = x[i];
  const u16 hi = f2bf(v);
  xh[i] = hi;
  xl[i] = f2bf(v - bf2f(hi));
}

// W_Q/K/V (H,E,D) f32 -> BT planes [6144][2048] (row j = t*2048+h*128+d, col k=e), hi & lo
__global__ __launch_bounds__(256) void pack_qkv2(const float* __restrict__ WQ, const float* __restrict__ WK,
                                                 const float* __restrict__ WV,
                                                 u16* __restrict__ outh, u16* __restrict__ outl){
  __shared__ float t32[32][33];
  const int tid = threadIdx.x;
  const int tx = tid & 31, ty = tid >> 5;
  const int et = blockIdx.x >> 2, dt = blockIdx.x & 3;
  const int hh = blockIdx.y, tt = blockIdx.z;
  const float* W = (tt == 0 ? WQ : (tt == 1 ? WK : WV)) + (size_t)hh*2048*128;
  #pragma unroll
  for (int i = 0; i < 4; i++)
    t32[ty + i*8][tx] = W[(size_t)(et*32 + ty + i*8)*128 + dt*32 + tx];
  __syncthreads();
  const int j0 = tt*2048 + hh*128 + dt*32;
  #pragma unroll
  for (int i = 0; i < 4; i++){
    const float v = t32[tx][ty + i*8];
    const u16 hi = f2bf(v);
    const u16 lo = f2bf(v - bf2f(hi));
    const size_t idx = (size_t)(j0 + ty + i*8)*2048 + (et*32 + tx);
    outh[idx] = hi; outl[idx] = lo;
  }
}

// in (R,C) f32 -> outh/outl (C,R) bf16 hi/lo planes (transpose + split)
__global__ __launch_bounds__(256) void tpack2(const float* __restrict__ in,
                                              u16* __restrict__ outh, u16* __restrict__ outl,
                                              int R, int C){
  __shared__ float t32[32][33];
  const int tid = threadIdx.x;
  const int tx = tid & 31, ty = tid >> 5;
  const int c0 = blockIdx.x*32, r0 = blockIdx.y*32;
  #pragma unroll
  for (int i = 0; i < 4; i++)
    t32[ty + i*8][tx] = in[(size_t)(r0 + ty + i*8)*C + c0 + tx];
  __syncthreads();
  #pragma unroll
  for (int i = 0; i < 4; i++){
    const float v = t32[tx][ty + i*8];
    const u16 hi = f2bf(v);
    const u16 lo = f2bf(v - bf2f(hi));
    const size_t idx = (size_t)(c0 + ty + i*8)*R + r0 + tx;
    outh[idx] = hi; outl[idx] = lo;
  }
}

// ---------- gemm8: 256x256 tile, BK=64, 8 waves, multi-phase schedule ----------
// C(M,N) = A(M,K)*BT(N,K)^T with hi/lo plane phases (virtual K = NS*K).
// SK-way split-K (SK=1 or 4). EPI 0: QKV split-write  2: bias+relu->bf16  4: f32 partial.
template<int NS, int EPI, int SK>
__global__ __launch_bounds__(512, 2) void gemm8(
    const u16* __restrict__ Ah, const u16* __restrict__ Al,
    const u16* __restrict__ Bh, const u16* __restrict__ Bl,
    float* __restrict__ outf, u16* __restrict__ outb,
    const float* __restrict__ bias,
    u16* __restrict__ qh, u16* __restrict__ ql,
    u16* __restrict__ kh, u16* __restrict__ kl,
    u16* __restrict__ vTh, float* __restrict__ part,
    int M, int N, int K)
{
  __shared__ u16 LS[2][2][16384];   // [buf][A/B][256*64]
  const int tid = threadIdx.x;
  const int lane = tid & 63;
  const int w = tid >> 6;            // 0..7
  const int wr = w >> 2, wc = w & 3; // 2 x 4 wave grid
  const int l15 = lane & 15, lh = lane >> 4;
  const int nbx = N >> 8;
  int bsw = ((int)blockIdx.x & 7) * ((int)gridDim.x >> 3) + ((int)blockIdx.x >> 3);
  int slice = 0;
  if (SK == 4){ slice = bsw & 3; bsw >>= 2; }
  const int bx = bsw % nbx, by = bsw / nbx;
  const int m0 = by << 8, n0 = bx << 8;

  const int tiles_total = (NS * K) >> 6;
  const int nt = (SK == 4) ? (tiles_total >> 2) : tiles_total;
  const int t0 = (SK == 4) ? slice * nt : 0;

  auto stage = [&](int buf, int t){
    const int k0v = t << 6;
    const u16* Ap; const u16* Bp; int kk;
    if (NS == 1){ Ap = Ah; Bp = Bh; kk = k0v; }
    else if (NS == 2){
      if (k0v < K){ Ap = Ah; Bp = Bh; kk = k0v; }
      else        { Ap = Ah; Bp = Bl; kk = k0v - K; }
    } else {
      if (k0v < K)        { Ap = Ah; Bp = Bh; kk = k0v; }
      else if (k0v < 2*K) { Ap = Ah; Bp = Bl; kk = k0v - K; }
      else                { Ap = Al; Bp = Bh; kk = k0v - 2*K; }
    }
    u16* La = &LS[buf][0][0];
    u16* Lb = &LS[buf][1][0];
    #pragma unroll
    for (int q = 0; q < 4; q++){        // A tile 256 rows x 64 cols, chunk-swizzled source
      int s = q*512 + tid;
      int row = s >> 3, cc = (s & 7) ^ (row & 7);
      gload16(Ap + (size_t)(m0+row)*K + kk + cc*8, La + (q*512 + (tid & 448))*8);
    }
    #pragma unroll
    for (int q = 0; q < 4; q++){        // B tile 256 rows x 64 cols
      int s = q*512 + tid;
      int row = s >> 3, cc = (s & 7) ^ (row & 7);
      gload16(Bp + (size_t)(n0+row)*K + kk + cc*8, Lb + (q*512 + (tid & 448))*8);
    }
  };

  f32x4 acc[8][4] = {};
  bf16x8 bfr[4][2];

  stage(0, t0);
  for (int lt = 0; lt < nt; ++lt){
    const int buf = lt & 1;
    // burst-issue next tile into the other buffer (its previous reader closed by
    // the trailing barrier of tile lt-1), then counted wait: tile lt's 8 loads done,
    // tile lt+1's 8 stay in flight across all barriers below.
    if (lt + 1 < nt){
      stage(buf ^ 1, t0 + lt + 1);
      asm volatile("s_waitcnt vmcnt(8)" ::: "memory");
    } else {
      asm volatile("s_waitcnt vmcnt(0)" ::: "memory");
    }
    asm volatile("" ::: "memory");
    __builtin_amdgcn_s_barrier();
    asm volatile("" ::: "memory");

    const u16* La = &LS[buf][0][0];
    const u16* Lb = &LS[buf][1][0];
    // B fragments persist in registers for the whole tile
    #pragma unroll
    for (int n = 0; n < 4; n++){
      int br = wc*64 + n*16 + l15;
      #pragma unroll
      for (int kt = 0; kt < 2; kt++){
        int c = (kt*4 + lh) ^ (br & 7);
        bfr[n][kt] = *(const bf16x8*)(Lb + br*64 + c*8);
      }
    }
    #pragma unroll
    for (int p = 0; p < 4; p++){
      if (p){
        asm volatile("" ::: "memory");
        __builtin_amdgcn_s_barrier();     // phase boundary (scheduling only)
        asm volatile("" ::: "memory");
      }
      bf16x8 af[2][2];
      #pragma unroll
      for (int i = 0; i < 2; i++){
        int ar = wr*128 + (2*p+i)*16 + l15;
        #pragma unroll
        for (int kt = 0; kt < 2; kt++){
          int c = (kt*4 + lh) ^ (ar & 7);
          af[i][kt] = *(const bf16x8*)(La + ar*64 + c*8);
        }
      }
      asm volatile("s_waitcnt lgkmcnt(0)" ::: "memory");
      __builtin_amdgcn_sched_barrier(0);
      __builtin_amdgcn_s_setprio(1);
      #pragma unroll
      for (int i = 0; i < 2; i++)
        #pragma unroll
        for (int n = 0; n < 4; n++)
          #pragma unroll
          for (int kt = 0; kt < 2; kt++)
            acc[2*p+i][n] = MFMA_B16(af[i][kt], bfr[n][kt], acc[2*p+i][n]);
      __builtin_amdgcn_s_setprio(0);
    }
    asm volatile("" ::: "memory");
    __builtin_amdgcn_s_barrier();        // close reads of buf before its next overwrite
    asm volatile("" ::: "memory");
  }

  // epilogue: C/D layout col=lane&15, row=(lane>>4)*4+r
  #pragma unroll
  for (int m = 0; m < 8; m++){
    #pragma unroll
    for (int n = 0; n < 4; n++){
      const int rbase = m0 + wr*128 + m*16 + lh*4;
      const int col = n0 + wc*64 + n*16 + l15;
      if (EPI == 0){
        const int plane = col >> 11;      // 0=Q 1=K 2=V
        const int cj = col & 2047;
        if (plane == 2){
          ushort4 h4 = make_ushort4(f2bf(acc[m][n][0]), f2bf(acc[m][n][1]),
                                    f2bf(acc[m][n][2]), f2bf(acc[m][n][3]));
          *(ushort4*)(vTh + (size_t)cj*2048 + rbase) = h4;   // V transposed [hd][n]
        } else {
          u16* hp = (plane == 0) ? qh : kh;
          u16* lp = (plane == 0) ? ql : kl;
          #pragma unroll
          for (int r = 0; r < 4; r++){
            float v = acc[m][n][r];
            u16 hi = f2bf(v);
            u16 lo = f2bf(v - bf2f(hi));
            hp[(size_t)(rbase+r)*2048 + cj] = hi;
            lp[(size_t)(rbase+r)*2048 + cj] = lo;
          }
        }
      } else if (EPI == 2){
        const float b = bias[col];
        #pragma unroll
        for (int r = 0; r < 4; r++){
          float v = acc[m][n][r] + b;
          outb[(size_t)(rbase+r)*N + col] = f2bf(v > 0.f ? v : 0.f);
        }
      } else {   // EPI == 4: split-K raw partial
        float* dst = (slice < 3) ? (part + (size_t)slice*M*N) : outf;
        #pragma unroll
        for (int r = 0; r < 4; r++)
          dst[(size_t)(rbase+r)*N + col] = acc[m][n][r];
      }
    }
  }
}

// PR = PR(slice3 partial) + p0+p1+p2 + H1 + b2   (float4 per thread)
__global__ __launch_bounds__(256) void ffn2_reduce(
    float* __restrict__ PR, const float* __restrict__ part,
    const float* __restrict__ H1, const float* __restrict__ b2)
{
  const size_t i4 = (size_t)blockIdx.x*256 + threadIdx.x;   // float4 index
  const size_t base = i4*4;
  const int col = (int)(base & 2047);
  float4 a  = ((float4*)PR)[i4];
  float4 p0 = ((const float4*)part)[i4];
  float4 p1 = ((const float4*)(part + 4194304))[i4];
  float4 p2 = ((const float4*)(part + 8388608))[i4];
  float4 h  = ((const float4*)H1)[i4];
  float4 b  = *(const float4*)(b2 + col);
  a.x = a.x + p0.x + p1.x + p2.x + h.x + b.x;
  a.y = a.y + p0.y + p1.y + p2.y + h.y + b.y;
  a.z = a.z + p0.z + p1.z + p2.z + h.z + b.z;
  a.w = a.w + p0.w + p1.w + p2.w + h.w + b.w;
  ((float4*)PR)[i4] = a;
}

// ---------- 2-phase 128x128 GEMM (kept for the pool projection) ----------
// EPI 1: f32 + res
__global__ __launch_bounds__(256) void gemm_bt(
    const u16* __restrict__ Ah, const u16* __restrict__ Bh,
    float* __restrict__ outf, const float* __restrict__ res,
    int M, int N, int K)
{
  __shared__ u16 As[2][128*64];
  __shared__ u16 Bs[2][128*64];
  const int tid = threadIdx.x;
  const int lane = tid & 63;
  const int w = tid >> 6;
  const int l15 = lane & 15, lh = lane >> 4;
  const int nbx = N >> 7;
  const int bsw = ((int)blockIdx.x & 7)*((int)gridDim.x >> 3) + ((int)blockIdx.x >> 3);
  const int bx = bsw % nbx, by = bsw / nbx;
  const int m0 = by << 7, n0 = bx << 7;
  const int wm = (w >> 1) << 6, wn = (w & 1) << 6;

  f32x4 acc[4][4] = {};
  const int NT = K >> 6;

  auto stage = [&](int buf, int kk){
    u16* Asb = &As[buf][0];
    u16* Bsb = &Bs[buf][0];
    #pragma unroll
    for (int q = 0; q < 4; q++){
      int s = q*256 + tid;
      int row = s >> 3, cc = (s & 7) ^ (row & 7);
      gload16(Ah + (size_t)(m0+row)*K + kk + cc*8, Asb + (q*256 + (tid & 192))*8);
    }
    #pragma unroll
    for (int q = 0; q < 4; q++){
      int s = q*256 + tid;
      int row = s >> 3, cc = (s & 7) ^ (row & 7);
      gload16(Bh + (size_t)(n0+row)*K + kk + cc*8, Bsb + (q*256 + (tid & 192))*8);
    }
  };

  stage(0, 0);
  for (int t = 0; t < NT; ++t){
    const int cur = t & 1;
    if (t + 1 < NT){
      stage(cur ^ 1, (t + 1) << 6);
      asm volatile("s_waitcnt vmcnt(8)" ::: "memory");
    } else {
      asm volatile("s_waitcnt vmcnt(0)" ::: "memory");
    }
    __builtin_amdgcn_s_barrier();
    asm volatile("" ::: "memory");

    const u16* Asb = &As[cur][0];
    const u16* Bsb = &Bs[cur][0];
    #pragma unroll
    for (int kt = 0; kt < 2; kt++){
      bf16x8 af[4], bfr[4];
      #pragma unroll
      for (int m = 0; m < 4; m++){
        int row = wm + m*16 + l15;
        int c = (kt*4 + lh) ^ (row & 7);
        af[m] = *(const bf16x8*)(Asb + row*64 + c*8);
      }
      #pragma unroll
      for (int n = 0; n < 4; n++){
        int row = wn + n*16 + l15;
        int c = (kt*4 + lh) ^ (row & 7);
        bfr[n] = *(const bf16x8*)(Bsb + row*64 + c*8);
      }
      #pragma unroll
      for (int m = 0; m < 4; m++)
        #pragma unroll
        for (int n = 0; n < 4; n++)
          acc[m][n] = MFMA_B16(af[m], bfr[n], acc[m][n]);
    }
    asm volatile("" ::: "memory");
    __builtin_amdgcn_s_barrier();
    asm volatile("" ::: "memory");
  }

  #pragma unroll
  for (int m = 0; m < 4; m++){
    #pragma unroll
    for (int n = 0; n < 4; n++){
      const int rbase = m0 + wm + m*16 + lh*4;
      const int col = n0 + wn + n*16 + l15;
      #pragma unroll
      for (int r = 0; r < 4; r++){
        size_t idx = (size_t)(rbase+r)*N + col;
        outf[idx] = acc[m][n][r] + res[idx];
      }
    }
  }
}

// ---------- flash attention (causal), 4 waves x 16 q-rows, KV tile 64 ----------
__global__ __launch_bounds__(256) void attn_k(
    const u16* __restrict__ qh, const u16* __restrict__ ql,
    const u16* __restrict__ kh, const u16* __restrict__ kl,
    const u16* __restrict__ vT, u16* __restrict__ atth)
{
  __shared__ u16 Khs[64*128];
  __shared__ u16 Kls[64*128];
  __shared__ u16 Vhs[128*64];
  __shared__ u16 Phs[4*16*64];

  const int tid = threadIdx.x;
  const int lane = tid & 63;
  const int w = tid >> 6;
  const int l15 = lane & 15, lh = lane >> 4;
  const int h = blockIdx.y;
  const int qb = blockIdx.x;
  const int qbase = qb << 6;
  const float scale = 0.088388347648318447f;  // 1/sqrt(128)

  bf16x8 qfh[4], qfl[4];
  {
    const int qrow = qbase + w*16 + l15;
    const u16* ph = qh + (size_t)qrow*2048 + h*128 + lh*8;
    const u16* pl = ql + (size_t)qrow*2048 + h*128 + lh*8;
    #pragma unroll
    for (int kt = 0; kt < 4; kt++){
      qfh[kt] = *(const bf16x8*)(ph + kt*32);
      qfl[kt] = *(const bf16x8*)(pl + kt*32);
    }
  }

  f32x4 acco[8] = {};
  float mrun[4] = {-1e30f,-1e30f,-1e30f,-1e30f};
  float lrun[4] = {0.f,0.f,0.f,0.f};
  const int qrow0 = qbase + w*16 + lh*4;
  u16* pwh = Phs + w*1024;

  const int nkv = qb + 1;
  for (int kvt = 0; kvt < nkv; kvt++){
    const int kv0 = kvt << 6;
    __syncthreads();
    #pragma unroll
    for (int q = 0; q < 4; q++){
      int s = q*256 + tid;
      int row = s >> 4, c = (s & 15) ^ (row & 7);
      gload16(kh + (size_t)(kv0+row)*2048 + h*128 + c*8, Khs + (q*256 + (tid & 192))*8);
    }
    #pragma unroll
    for (int q = 0; q < 4; q++){
      int s = q*256 + tid;
      int row = s >> 4, c = (s & 15) ^ (row & 7);
      gload16(kl + (size_t)(kv0+row)*2048 + h*128 + c*8, Kls + (q*256 + (tid & 192))*8);
    }
    #pragma unroll
    for (int q = 0; q < 4; q++){
      int s = q*256 + tid;
      int d = s >> 3, c = (s & 7) ^ (d & 7);
      gload16(vT + (size_t)(h*128+d)*2048 + kv0 + c*8, Vhs + (q*256 + (tid & 192))*8);
    }
    asm volatile("s_waitcnt vmcnt(0)" ::: "memory");
    __syncthreads();

    // S = Q K^T (split-2: hi*hi + hi*lo + lo*hi)
    f32x4 sac[4] = {};
    __builtin_amdgcn_s_setprio(1);
    #pragma unroll
    for (int n = 0; n < 4; n++){
      const int kvr = n*16 + l15;
      const u16* kb  = Khs + kvr*128;
      const u16* klb = Kls + kvr*128;
      const int sw = kvr & 7;
      #pragma unroll
      for (int kt = 0; kt < 4; kt++){
        const int c = (kt*4 + lh) ^ sw;
        bf16x8 bh = *(const bf16x8*)(kb + c*8);
        bf16x8 bl = *(const bf16x8*)(klb + c*8);
        sac[n] = MFMA_B16(qfh[kt], bh, sac[n]);
        sac[n] = MFMA_B16(qfh[kt], bl, sac[n]);
        sac[n] = MFMA_B16(qfl[kt], bh, sac[n]);
      }
    }
    __builtin_amdgcn_s_setprio(0);

    // online softmax (fp32)
    float p[4][4];
    float tm[4] = {-1e30f,-1e30f,-1e30f,-1e30f};
    #pragma unroll
    for (int n = 0; n < 4; n++){
      const int kvg = kv0 + n*16 + l15;
      #pragma unroll
      for (int r = 0; r < 4; r++){
        float s = sac[n][r] * scale;
        if (kvg > qrow0 + r) s = -1e30f;   // causal mask
        p[n][r] = s;
        tm[r] = fmaxf(tm[r], s);
      }
    }
    #pragma unroll
    for (int r = 0; r < 4; r++){
      tm[r] = fmaxf(tm[r], __shfl_xor(tm[r], 1));
      tm[r] = fmaxf(tm[r], __shfl_xor(tm[r], 2));
      tm[r] = fmaxf(tm[r], __shfl_xor(tm[r], 4));
      tm[r] = fmaxf(tm[r], __shfl_xor(tm[r], 8));
    }
    float corr[4];
    #pragma unroll
    for (int r = 0; r < 4; r++){
      float mn = fmaxf(mrun[r], tm[r]);
      corr[r] = __expf(mrun[r] - mn);
      mrun[r] = mn;
    }
    #pragma unroll
    for (int r = 0; r < 4; r++){
      float sum = 0.f;
      #pragma unroll
      for (int n = 0; n < 4; n++){
        float pv = __expf(p[n][r] - mrun[r]);
        p[n][r] = pv;
        sum += pv;
      }
      sum += __shfl_xor(sum, 1);
      sum += __shfl_xor(sum, 2);
      sum += __shfl_xor(sum, 4);
      sum += __shfl_xor(sum, 8);
      lrun[r] = lrun[r]*corr[r] + sum;
    }
    #pragma unroll
    for (int nn = 0; nn < 8; nn++)
      #pragma unroll
      for (int r = 0; r < 4; r++)
        acco[nn][r] *= corr[r];

    // P -> LDS (bf16, chunk-swizzled), per-wave private region
    #pragma unroll
    for (int n = 0; n < 4; n++){
      const int colb = n*16 + l15;
      #pragma unroll
      for (int r = 0; r < 4; r++){
        const int row = lh*4 + r;
        const int off = row*64 + (((colb>>3) ^ (row&7))<<3) + (colb&7);
        pwh[off] = f2bf(p[n][r]);
      }
    }
    asm volatile("" ::: "memory");

    // O += P V
    __builtin_amdgcn_s_setprio(1);
    #pragma unroll
    for (int kt2 = 0; kt2 < 2; kt2++){
      const int ac = (kt2*4 + lh) ^ (l15 & 7);
      bf16x8 afh = *(const bf16x8*)(pwh + l15*64 + ac*8);
      #pragma unroll
      for (int n = 0; n < 8; n++){
        const int d = n*16 + l15;
        const int c = (kt2*4 + lh) ^ (d & 7);
        bf16x8 bvh = *(const bf16x8*)(Vhs + d*64 + c*8);
        acco[n] = MFMA_B16(afh, bvh, acco[n]);
      }
    }
    __builtin_amdgcn_s_setprio(0);
  }

  #pragma unroll
  for (int n = 0; n < 8; n++){
    const int col = h*128 + n*16 + l15;
    #pragma unroll
    for (int r = 0; r < 4; r++){
      atth[(size_t)(qrow0+r)*2048 + col] = f2bf(acco[n][r] / lrun[r]);
    }
  }
}

// ---------- LayerNorm (two-pass, fp32); WSPLIT=1 also writes bf16 hi (and lo if given) ----------
template<int WSPLIT>
__global__ __launch_bounds__(256) void ln_k(
    const float* __restrict__ in, float* __restrict__ outf,
    u16* __restrict__ outh, u16* __restrict__ outl,
    const float* __restrict__ gptr, const float* __restrict__ beta)
{
  const int tid = threadIdx.x;
  const int lane = tid & 63;
  const int w = tid >> 6;
  const int row = blockIdx.x;
  const float4* xr = (const float4*)(in + (size_t)row*2048);
  float4 a = xr[tid];
  float4 b = xr[tid + 256];
  float s = a.x+a.y+a.z+a.w + b.x+b.y+b.z+b.w;
  #pragma unroll
  for (int off = 32; off; off >>= 1) s += __shfl_xor(s, off);
  __shared__ float red[8];
  if (lane == 0) red[w] = s;
  __syncthreads();
  const float mean = (red[0]+red[1]+red[2]+red[3]) * (1.0f/2048.0f);
  float q =
    (a.x-mean)*(a.x-mean) + (a.y-mean)*(a.y-mean) + (a.z-mean)*(a.z-mean) + (a.w-mean)*(a.w-mean) +
    (b.x-mean)*(b.x-mean) + (b.y-mean)*(b.y-mean) + (b.z-mean)*(b.z-mean) + (b.w-mean)*(b.w-mean);
  #pragma unroll
  for (int off = 32; off; off >>= 1) q += __shfl_xor(q, off);
  if (lane == 0) red[4 + w] = q;
  __syncthreads();
  const float var = (red[4]+red[5]+red[6]+red[7]) * (1.0f/2048.0f);
  const float sc = rsqrtf(var + 1e-5f) * gptr[0];
  const float4 be0 = ((const float4*)beta)[tid];
  const float4 be1 = ((const float4*)beta)[tid + 256];
  float4 o0, o1;
  o0.x = (a.x-mean)*sc + be0.x; o0.y = (a.y-mean)*sc + be0.y;
  o0.z = (a.z-mean)*sc + be0.z; o0.w = (a.w-mean)*sc + be0.w;
  o1.x = (b.x-mean)*sc + be1.x; o1.y = (b.y-mean)*sc + be1.y;
  o1.z = (b.z-mean)*sc + be1.z; o1.w = (b.w-mean)*sc + be1.w;
  float4* orow = (float4*)(outf + (size_t)row*2048);
  orow[tid] = o0; orow[tid+256] = o1;
  if (WSPLIT){
    ushort4 h0 = make_ushort4(f2bf(o0.x), f2bf(o0.y), f2bf(o0.z), f2bf(o0.w));
    ushort4 h1 = make_ushort4(f2bf(o1.x), f2bf(o1.y), f2bf(o1.z), f2bf(o1.w));
    ushort4* hrow = (ushort4*)(outh + (size_t)row*2048);
    hrow[tid] = h0; hrow[tid+256] = h1;
    if (outl){
      ushort4 L0 = make_ushort4(f2bf(o0.x - bf2f(h0.x)), f2bf(o0.y - bf2f(h0.y)),
                                f2bf(o0.z - bf2f(h0.z)), f2bf(o0.w - bf2f(h0.w)));
      ushort4 L1 = make_ushort4(f2bf(o1.x - bf2f(h1.x)), f2bf(o1.y - bf2f(h1.y)),
                                f2bf(o1.z - bf2f(h1.z)), f2bf(o1.w - bf2f(h1.w)));
      ushort4* lrow = (ushort4*)(outl + (size_t)row*2048);
      lrow[tid] = L0; lrow[tid+256] = L1;
    }
  }
}

// ---------- launch ----------
extern "C" void kernel_launch(void* const* d_in, const int* in_sizes, int n_in,
                              void* d_out, int out_size, void* d_ws, size_t ws_size,
                              hipStream_t stream)
{
  const float* x   = (const float*)d_in[0];
  const float* WQ  = (const float*)d_in[1];
  const float* WK  = (const float*)d_in[2];
  const float* WV  = (const float*)d_in[3];
  const float* WP  = (const float*)d_in[4];
  const float* W1  = (const float*)d_in[5];
  const float* b1  = (const float*)d_in[6];
  const float* W2  = (const float*)d_in[7];
  const float* b2  = (const float*)d_in[8];
  const float* gam = (const float*)d_in[9];
  const float* bet = (const float*)d_in[10];
  float* out = (float*)d_out;
  (void)in_sizes; (void)n_in; (void)out_size; (void)ws_size;

  const size_t NP = 2048ull*2048;          // elements per 2048x2048 plane
  char* pR1 = (char*)d_ws;                 // 64 MiB: weight hi plane @0, lo plane @32MiB
  char* pR2 = pR1 + (64ull<<20);           // 32 MiB: xh,xl | later a1 (2048x8192)
  char* pR3 = pR2 + (32ull<<20);           // 48 MiB: q/k hi-lo + vT | Hh,Hl | FFN2 partials
  char* pR4 = pR3 + (48ull<<20);           // 16 MiB: ATTh | later H1 (fp32)
  char* pR5 = pR4 + (16ull<<20);           // 16 MiB: PR (fp32)

  u16* Wh   = (u16*)pR1;
  u16* Wl   = (u16*)(pR1 + (32ull<<20));
  u16* xh   = (u16*)pR2;
  u16* xl   = xh + NP;
  u16* a1   = (u16*)pR2;                   // 2048x8192 bf16 (after xh/xl dead)
  u16* qh_  = (u16*)pR3;
  u16* ql_  = qh_ + NP;
  u16* kh_  = ql_ + NP;
  u16* kl_  = kh_ + NP;
  u16* vT_  = kl_ + NP;
  u16* Hh   = (u16*)pR3;                   // after attn done
  float* part = (float*)pR3;               // FFN2 partials (3 x 16 MiB), after FFN1 done
  u16* ATTh = (u16*)pR4;
  float* H1 = (float*)pR4;                 // after pool done
  float* PR = (float*)pR5;

  // 1) pack x and W_QKV into hi/lo planes
  pack_x2 <<<2048*2048/256, 256, 0, stream>>>(x, xh, xl);
  pack_qkv2<<<dim3(256,16,3), 256, 0, stream>>>(WQ, WK, WV, Wh, Wl);
  // 2) QKV projection, 3-term split (M=2048, N=6144, K=2048), 8-phase 256^2
  gemm8<3,0,1><<<192, 512, 0, stream>>>(xh, xl, Wh, Wl, nullptr, nullptr, nullptr,
                                        qh_, ql_, kh_, kl_, vT_, nullptr, 2048, 6144, 2048);
  // 3) causal flash attention -> ATTh (bf16 [n][h*128+d])
  attn_k<<<dim3(32,16), 256, 0, stream>>>(qh_, ql_, kh_, kl_, vT_, ATTh);
  // 4) pool GEMM (1-term) + residual: PR = x + ATT @ W_Pool   (128^2 2-phase)
  tpack2<<<dim3(64,64), 256, 0, stream>>>(WP, Wh, Wl, 2048, 2048);
  gemm_bt<<<256, 256, 0, stream>>>(ATTh, Wh, PR, x, 2048, 2048, 2048);
  // 5) LN1 -> H1 (fp32) + Hh (bf16; lo plane not needed)
  ln_k<1><<<2048, 256, 0, stream>>>(PR, H1, Hh, nullptr, gam, bet);
  // 6) FFN1 (1-term): a1 = relu(H @ W1 + b1) -> bf16, 8-phase 256^2
  tpack2<<<dim3(256,64), 256, 0, stream>>>(W1, Wh, Wl, 2048, 8192);
  gemm8<1,2,1><<<256, 512, 0, stream>>>(Hh, nullptr, Wh, nullptr, nullptr, a1, b1,
                                        nullptr, nullptr, nullptr, nullptr, nullptr, nullptr,
                                        2048, 8192, 2048);
  // 7) FFN2 (2-term) split-K x4 -> partials; then reduce: PR = sum(parts) + H1 + b2
  tpack2<<<dim3(64,256), 256, 0, stream>>>(W2, Wh, Wl, 8192, 2048);
  gemm8<2,4,4><<<256, 512, 0, stream>>>(a1, nullptr, Wh, Wl, PR, nullptr, nullptr,
                                        nullptr, nullptr, nullptr, nullptr, nullptr, part,
                                        2048, 2048, 8192);
  ffn2_reduce<<<4096, 256, 0, stream>>>(PR, part, H1, b2);
  // 8) LN2 -> out
  ln_k<0><<<2048, 256, 0, stream>>>(PR, out, nullptr, nullptr, gam, bet);
}